// Round 16
// baseline (380.354 us; speedup 1.0000x reference)
//
#include <hip/hip_runtime.h>
#include <hip/hip_bf16.h>

// ---------------------------------------------------------------------------
// 3-layer GCN + global mean pool, MI355X — round 15: channel-sliced XCD agg
//
// R14 post-mortem: aggs pinned by compulsory fetch — every XCD L2 refills the
// whole 12.8 MB h (random gathers). R15: partition channels into 32-wide
// slices (3.2 MB each, fits a 4 MiB XCD L2); blockIdx&7 swizzle pins each
// slice to an XCD pair -> per-XCD working set = one slice. Per-edge read =
// one 64B line. EXEC-safe shfl (R14-proven). GEMM/build/pool unchanged.
// ---------------------------------------------------------------------------

constexpr int NN   = 50000;   // nodes (divisible by 16)
constexpr int NE   = 800000;  // edges
constexpr int GG   = 512;     // graphs
constexpr int SLOT = 64;      // padded slots/node

constexpr int NBUCK  = (NN + 127) / 128;       // 391 buckets of 128 nodes
constexpr int BCAP   = 2560;                   // per-bucket capacity
constexpr int EPB    = 2048;                   // edges per binA block
constexpr int NBLK_A = (NE + EPB - 1) / EPB;   // 391 blocks
constexpr int NCTRL  = NBUCK + 2 * GG;         // cursor + gstart + gend words

using shortx8 = __attribute__((ext_vector_type(8))) short;   // 8 bf16 = 4 VGPRs
using f32x4   = __attribute__((ext_vector_type(4))) float;

__device__ __forceinline__ unsigned short f2bf(float f) {
    __hip_bfloat16 h = __float2bfloat16(f);   // RNE
    return *(unsigned short*)&h;
}
__device__ __forceinline__ float bf2f(unsigned u16) {
    return __uint_as_float(u16 << 16);
}

// ---------------- W prep (bf16 col-major) + ctrl zeroing (fused memset) ----------
__global__ void k_wprep(const float* __restrict__ W1, const float* __restrict__ W2,
                        const float* __restrict__ W3, unsigned short* __restrict__ WT1,
                        unsigned short* __restrict__ WT2, unsigned short* __restrict__ WT3,
                        int* __restrict__ ctrl) {
    int i = blockIdx.x * blockDim.x + threadIdx.x;
    if (i < NCTRL) ctrl[i] = 0;
    if (i < 128 * 128) {
        int k = i >> 7, n = i & 127;
        WT1[n * 128 + k] = f2bf(W1[i]);
        WT2[n * 128 + k] = f2bf(W2[i]);
    }
    if (i < 128 * 64) {
        int k = i >> 6, n = i & 63;
        WT3[n * 128 + k] = f2bf(W3[i]);
    }
}

// ---------------- build phase A: bin edges by 128-node bucket (R11-proven) -------
__global__ __launch_bounds__(256) void k_binA(const int* __restrict__ src,
                                              const int* __restrict__ dst,
                                              int* __restrict__ cursor,
                                              unsigned* __restrict__ ebuf) {
    __shared__ int hist[512];
    __shared__ int lstart[512];
    __shared__ int gbase[NBUCK];
    __shared__ int lcur[NBUCK];
    __shared__ unsigned stage[EPB];

    int tid = threadIdx.x;
    int e0 = blockIdx.x * EPB;
    int nloc = min(EPB, NE - e0);

    hist[tid] = 0;
    hist[tid + 256] = 0;
    __syncthreads();
    for (int k = 0; k < EPB / 256; ++k) {
        int e = e0 + k * 256 + tid;
        if (e < NE) atomicAdd(&hist[dst[e] >> 7], 1);
    }
    __syncthreads();

    int v0 = hist[tid];
    lstart[tid] = v0;
    __syncthreads();
    for (int off = 1; off < 256; off <<= 1) {
        int t = (tid >= off) ? lstart[tid - off] : 0;
        __syncthreads();
        lstart[tid] += t;
        __syncthreads();
    }
    int v1 = hist[256 + tid];
    lstart[256 + tid] = v1;
    __syncthreads();
    for (int off = 1; off < 256; off <<= 1) {
        int t = (tid >= off) ? lstart[256 + tid - off] : 0;
        __syncthreads();
        lstart[256 + tid] += t;
        __syncthreads();
    }
    int lowTotal = lstart[255];
    int ex0 = lstart[tid] - v0;
    int ex1 = lstart[256 + tid] - v1 + lowTotal;
    __syncthreads();
    lstart[tid] = ex0;
    lstart[256 + tid] = ex1;
    __syncthreads();

    for (int i = tid; i < NBUCK; i += 256) {
        int h = hist[i];
        gbase[i] = (h > 0) ? atomicAdd(&cursor[i], h) : 0;
        lcur[i] = lstart[i];
    }
    __syncthreads();

    for (int k = 0; k < EPB / 256; ++k) {
        int e = e0 + k * 256 + tid;
        if (e < NE) {
            int d = dst[e];
            int pos = atomicAdd(&lcur[d >> 7], 1);
            stage[pos] = (unsigned)src[e] | ((unsigned)d << 16);
        }
    }
    __syncthreads();

    for (int i = tid; i < nloc; i += 256) {
        unsigned rec = stage[i];
        int bk = rec >> 23;
        int gpos = gbase[bk] + (i - lstart[bk]);
        if (gpos < BCAP) ebuf[(size_t)bk * BCAP + gpos] = rec;
    }
}

// ---------------- build phase B: per-bucket CSR in LDS + aux (R10-proven) --------
__global__ __launch_bounds__(256) void k_binB(const int* __restrict__ cursor,
                                              const unsigned* __restrict__ ebuf,
                                              int* __restrict__ cnt,
                                              int* __restrict__ csr_idx,
                                              float* __restrict__ dinv,
                                              const int* __restrict__ batch,
                                              int* __restrict__ gstart,
                                              int* __restrict__ gend) {
    __shared__ unsigned stage[BCAP];
    __shared__ unsigned short ordered[BCAP];
    __shared__ int ncnt[128];
    __shared__ int nstart[128];
    __shared__ int ncur[128];

    int bk = blockIdx.x;
    int tid = threadIdx.x;
    int n0 = bk << 7;
    int count = min(cursor[bk], BCAP);

    if (tid < 128) ncnt[tid] = 0;
    __syncthreads();
    for (int i = tid; i < count; i += 256) {
        unsigned rec = ebuf[(size_t)bk * BCAP + i];
        stage[i] = rec;
        atomicAdd(&ncnt[(rec >> 16) & 127], 1);
    }
    __syncthreads();
    if (tid < 128) nstart[tid] = ncnt[tid];
    __syncthreads();
    for (int off = 1; off < 128; off <<= 1) {
        int t = (tid >= off && tid < 128) ? nstart[tid - off] : 0;
        __syncthreads();
        if (tid < 128) nstart[tid] += t;
        __syncthreads();
    }
    if (tid < 128) { nstart[tid] -= ncnt[tid]; ncur[tid] = nstart[tid]; }
    __syncthreads();
    for (int i = tid; i < count; i += 256) {
        unsigned rec = stage[i];
        int nl = (rec >> 16) & 127;
        int p = atomicAdd(&ncur[nl], 1);
        ordered[p] = (unsigned short)(rec & 0xFFFFu);
    }
    __syncthreads();
    {
        int nl = tid >> 1, h = tid & 1;
        int node = n0 + nl;
        if (node < NN) {
            int c = min(ncnt[nl], SLOT);
            int s0 = nstart[nl];
            for (int k = h; k < c; k += 2)
                csr_idx[(size_t)node * SLOT + k] = ordered[s0 + k];
        }
    }
    if (tid < 128) {
        int node = n0 + tid;
        if (node < NN) {
            int c = ncnt[tid];
            cnt[node] = c;
            dinv[node] = rsqrtf((float)c + 1.0f);   // +1 self loop
            int b = batch[node];
            if (node == 0 || batch[node - 1] != b) gstart[b] = node;
            if (node == NN - 1 || batch[node + 1] != b) gend[b] = node + 1;
        }
    }
}

// ---------------- MFMA GEMM (R12-proven): out16[NN,DO] = A[NN,128] @ W ----------
template <int DO, bool AFP32>
__global__ __launch_bounds__(256) void k_gemm_mfma(const void* __restrict__ Ain,
                                                   const unsigned short* __restrict__ WT,
                                                   unsigned short* __restrict__ out16) {
    int tid = threadIdx.x;
    int wave = tid >> 6, lane = tid & 63;
    int row0 = blockIdx.x * 64 + wave * 16;
    if (row0 >= NN) return;
    int lrow = lane & 15;
    int lk8 = lane >> 4;
    int row = row0 + lrow;

    shortx8 afrag[4];
    if constexpr (AFP32) {
        const float* A = (const float*)Ain;
#pragma unroll
        for (int ks = 0; ks < 4; ++ks) {
            int k0 = ks * 32 + lk8 * 8;
            float4 f0 = *(const float4*)&A[(size_t)row * 128 + k0];
            float4 f1 = *(const float4*)&A[(size_t)row * 128 + k0 + 4];
            union { shortx8 v; unsigned short u[8]; } t;
            t.u[0] = f2bf(f0.x); t.u[1] = f2bf(f0.y);
            t.u[2] = f2bf(f0.z); t.u[3] = f2bf(f0.w);
            t.u[4] = f2bf(f1.x); t.u[5] = f2bf(f1.y);
            t.u[6] = f2bf(f1.z); t.u[7] = f2bf(f1.w);
            afrag[ks] = t.v;
        }
    } else {
        const unsigned short* A = (const unsigned short*)Ain;
#pragma unroll
        for (int ks = 0; ks < 4; ++ks)
            afrag[ks] = *(const shortx8*)&A[(size_t)row * 128 + ks * 32 + lk8 * 8];
    }

    constexpr int NT = DO / 16;
    f32x4 acc[NT];
#pragma unroll
    for (int t = 0; t < NT; ++t) acc[t] = {0.f, 0.f, 0.f, 0.f};

#pragma unroll
    for (int t = 0; t < NT; ++t) {
#pragma unroll
        for (int ks = 0; ks < 4; ++ks) {
            shortx8 b = *(const shortx8*)&WT[(size_t)(t * 16 + lrow) * 128 + ks * 32 + lk8 * 8];
            acc[t] = __builtin_amdgcn_mfma_f32_16x16x32_bf16(afrag[ks], b, acc[t], 0, 0, 0);
        }
    }

#pragma unroll
    for (int t = 0; t < NT; ++t) {
#pragma unroll
        for (int r = 0; r < 4; ++r) {
            int orow = row0 + lk8 * 4 + r;
            out16[(size_t)orow * DO + t * 16 + lrow] = f2bf(acc[t][r]);
        }
    }
}

// ---------------- agg DO=128, channel-sliced: wave = (node, 32ch slice) ----------
// blockIdx = g*8 + x; x&7 -> XCD slot; slice = x>>1 (2 XCDs per slice),
// sub = x&1 (node half). 16 edge streams x 4 lanes x 8ch. EXEC-safe shfl.
template <bool RELU>
__global__ __launch_bounds__(256) void k_agg128s(const unsigned short* __restrict__ h16,
                                                 const int* __restrict__ cnt,
                                                 const int* __restrict__ csr_idx,
                                                 const float* __restrict__ dinv,
                                                 const float* __restrict__ b,
                                                 unsigned short* __restrict__ out16) {
    int x = blockIdx.x & 7;
    int g = blockIdx.x >> 3;          // 0..6249
    int slice = x >> 1;               // 0..3
    int sub = x & 1;
    int wave = threadIdx.x >> 6;
    int lane = threadIdx.x & 63;
    int wid = sub * (NN / 2) + g * 4 + wave;   // node; g*4+wave < 25000
    int stream = lane >> 2;           // 0..15 edge streams
    int l4 = lane & 3;                // 4 lanes x 8 bf16 ch = 32 ch
    int n = min(cnt[wid], SLOT);      // wave-uniform
    float dv = dinv[wid];

    int rec = 0; float wl = 0.f;
    if (lane < n) {
        rec = csr_idx[wid * SLOT + lane];   // coalesced 256 B
        wl = dv * dinv[rec];
    }

    const uint4* h4 = (const uint4*)h16;    // row = 16 uint4
    int cb = slice * 4 + l4;                // uint4 offset within row
    float a0=0,a1=0,a2=0,a3=0,a4=0,a5=0,a6=0,a7=0;

    int jb_end = n & ~15;
    for (int jb = 0; jb < jb_end; jb += 16) {   // uniform: exec full at shfl
        int j = jb + stream;
        int s = __shfl(rec, j);
        float w = __shfl(wl, j);
        uint4 v = h4[(size_t)s * 16 + cb];      // one 64B line per edge (4 lanes)
        a0 += w * bf2f(v.x & 0xffff);
        a1 += w * bf2f(v.x >> 16);
        a2 += w * bf2f(v.y & 0xffff);
        a3 += w * bf2f(v.y >> 16);
        a4 += w * bf2f(v.z & 0xffff);
        a5 += w * bf2f(v.z >> 16);
        a6 += w * bf2f(v.w & 0xffff);
        a7 += w * bf2f(v.w >> 16);
    }
    {   // remainder (n - jb_end <= 15 edges): shfl converged, load guarded
        int i0 = jb_end + stream;
        int s = __shfl(rec, i0 & 63);
        float w = __shfl(wl, i0 & 63);
        if (i0 < n) {
            uint4 v = h4[(size_t)s * 16 + cb];
            a0 += w * bf2f(v.x & 0xffff);
            a1 += w * bf2f(v.x >> 16);
            a2 += w * bf2f(v.y & 0xffff);
            a3 += w * bf2f(v.y >> 16);
            a4 += w * bf2f(v.z & 0xffff);
            a5 += w * bf2f(v.z >> 16);
            a6 += w * bf2f(v.w & 0xffff);
            a7 += w * bf2f(v.w >> 16);
        }
    }
    // reduce 16 streams (same l4): strides 32,16,8,4
    a0 += __shfl_down(a0, 32); a1 += __shfl_down(a1, 32);
    a2 += __shfl_down(a2, 32); a3 += __shfl_down(a3, 32);
    a4 += __shfl_down(a4, 32); a5 += __shfl_down(a5, 32);
    a6 += __shfl_down(a6, 32); a7 += __shfl_down(a7, 32);
    a0 += __shfl_down(a0, 16); a1 += __shfl_down(a1, 16);
    a2 += __shfl_down(a2, 16); a3 += __shfl_down(a3, 16);
    a4 += __shfl_down(a4, 16); a5 += __shfl_down(a5, 16);
    a6 += __shfl_down(a6, 16); a7 += __shfl_down(a7, 16);
    a0 += __shfl_down(a0, 8);  a1 += __shfl_down(a1, 8);
    a2 += __shfl_down(a2, 8);  a3 += __shfl_down(a3, 8);
    a4 += __shfl_down(a4, 8);  a5 += __shfl_down(a5, 8);
    a6 += __shfl_down(a6, 8);  a7 += __shfl_down(a7, 8);
    a0 += __shfl_down(a0, 4);  a1 += __shfl_down(a1, 4);
    a2 += __shfl_down(a2, 4);  a3 += __shfl_down(a3, 4);
    a4 += __shfl_down(a4, 4);  a5 += __shfl_down(a5, 4);
    a6 += __shfl_down(a6, 4);  a7 += __shfl_down(a7, 4);
    if (lane < 4) {
        float d2 = dv * dv;
        uint4 hv = h4[(size_t)wid * 16 + slice * 4 + lane];
        int c0 = slice * 32 + lane * 8;
        float4 b0 = *(const float4*)&b[c0];
        float4 b1 = *(const float4*)&b[c0 + 4];
        a0 += d2 * bf2f(hv.x & 0xffff) + b0.x;
        a1 += d2 * bf2f(hv.x >> 16)    + b0.y;
        a2 += d2 * bf2f(hv.y & 0xffff) + b0.z;
        a3 += d2 * bf2f(hv.y >> 16)    + b0.w;
        a4 += d2 * bf2f(hv.z & 0xffff) + b1.x;
        a5 += d2 * bf2f(hv.z >> 16)    + b1.y;
        a6 += d2 * bf2f(hv.w & 0xffff) + b1.z;
        a7 += d2 * bf2f(hv.w >> 16)    + b1.w;
        if (RELU) {
            a0 = fmaxf(a0, 0.f); a1 = fmaxf(a1, 0.f); a2 = fmaxf(a2, 0.f); a3 = fmaxf(a3, 0.f);
            a4 = fmaxf(a4, 0.f); a5 = fmaxf(a5, 0.f); a6 = fmaxf(a6, 0.f); a7 = fmaxf(a7, 0.f);
        }
        union { uint4 v; unsigned short u[8]; } o;
        o.u[0] = f2bf(a0); o.u[1] = f2bf(a1); o.u[2] = f2bf(a2); o.u[3] = f2bf(a3);
        o.u[4] = f2bf(a4); o.u[5] = f2bf(a5); o.u[6] = f2bf(a6); o.u[7] = f2bf(a7);
        *(uint4*)&out16[(size_t)wid * 128 + c0] = o.v;
    }
}

// ---------------- agg DO=64, channel-sliced: 2 slices of 32ch, fp32 out ----------
__global__ __launch_bounds__(256) void k_agg64s(const unsigned short* __restrict__ h16,
                                                const int* __restrict__ cnt,
                                                const int* __restrict__ csr_idx,
                                                const float* __restrict__ dinv,
                                                const float* __restrict__ b,
                                                float* __restrict__ out) {
    int x = blockIdx.x & 7;
    int g = blockIdx.x >> 3;          // 0..3124
    int slice = x >> 2;               // 0..1 (4 XCDs per slice)
    int sub = x & 3;                  // node quarter
    int wave = threadIdx.x >> 6;
    int lane = threadIdx.x & 63;
    int wid = sub * (NN / 4) + g * 4 + wave;   // g*4+wave < 12500
    int stream = lane >> 2;
    int l4 = lane & 3;
    int n = min(cnt[wid], SLOT);
    float dv = dinv[wid];

    int rec = 0; float wl = 0.f;
    if (lane < n) {
        rec = csr_idx[wid * SLOT + lane];
        wl = dv * dinv[rec];
    }

    const uint4* h4 = (const uint4*)h16;    // row = 8 uint4
    int cb = slice * 4 + l4;
    float a0=0,a1=0,a2=0,a3=0,a4=0,a5=0,a6=0,a7=0;

    int jb_end = n & ~15;
    for (int jb = 0; jb < jb_end; jb += 16) {
        int j = jb + stream;
        int s = __shfl(rec, j);
        float w = __shfl(wl, j);
        uint4 v = h4[(size_t)s * 8 + cb];
        a0 += w * bf2f(v.x & 0xffff);
        a1 += w * bf2f(v.x >> 16);
        a2 += w * bf2f(v.y & 0xffff);
        a3 += w * bf2f(v.y >> 16);
        a4 += w * bf2f(v.z & 0xffff);
        a5 += w * bf2f(v.z >> 16);
        a6 += w * bf2f(v.w & 0xffff);
        a7 += w * bf2f(v.w >> 16);
    }
    {
        int i0 = jb_end + stream;
        int s = __shfl(rec, i0 & 63);
        float w = __shfl(wl, i0 & 63);
        if (i0 < n) {
            uint4 v = h4[(size_t)s * 8 + cb];
            a0 += w * bf2f(v.x & 0xffff);
            a1 += w * bf2f(v.x >> 16);
            a2 += w * bf2f(v.y & 0xffff);
            a3 += w * bf2f(v.y >> 16);
            a4 += w * bf2f(v.z & 0xffff);
            a5 += w * bf2f(v.z >> 16);
            a6 += w * bf2f(v.w & 0xffff);
            a7 += w * bf2f(v.w >> 16);
        }
    }
    a0 += __shfl_down(a0, 32); a1 += __shfl_down(a1, 32);
    a2 += __shfl_down(a2, 32); a3 += __shfl_down(a3, 32);
    a4 += __shfl_down(a4, 32); a5 += __shfl_down(a5, 32);
    a6 += __shfl_down(a6, 32); a7 += __shfl_down(a7, 32);
    a0 += __shfl_down(a0, 16); a1 += __shfl_down(a1, 16);
    a2 += __shfl_down(a2, 16); a3 += __shfl_down(a3, 16);
    a4 += __shfl_down(a4, 16); a5 += __shfl_down(a5, 16);
    a6 += __shfl_down(a6, 16); a7 += __shfl_down(a7, 16);
    a0 += __shfl_down(a0, 8);  a1 += __shfl_down(a1, 8);
    a2 += __shfl_down(a2, 8);  a3 += __shfl_down(a3, 8);
    a4 += __shfl_down(a4, 8);  a5 += __shfl_down(a5, 8);
    a6 += __shfl_down(a6, 8);  a7 += __shfl_down(a7, 8);
    a0 += __shfl_down(a0, 4);  a1 += __shfl_down(a1, 4);
    a2 += __shfl_down(a2, 4);  a3 += __shfl_down(a3, 4);
    a4 += __shfl_down(a4, 4);  a5 += __shfl_down(a5, 4);
    a6 += __shfl_down(a6, 4);  a7 += __shfl_down(a7, 4);
    if (lane < 4) {
        float d2 = dv * dv;
        uint4 hv = h4[(size_t)wid * 8 + slice * 4 + lane];
        int c0 = slice * 32 + lane * 8;
        float4 b0 = *(const float4*)&b[c0];
        float4 b1 = *(const float4*)&b[c0 + 4];
        a0 += d2 * bf2f(hv.x & 0xffff) + b0.x;
        a1 += d2 * bf2f(hv.x >> 16)    + b0.y;
        a2 += d2 * bf2f(hv.y & 0xffff) + b0.z;
        a3 += d2 * bf2f(hv.y >> 16)    + b0.w;
        a4 += d2 * bf2f(hv.z & 0xffff) + b1.x;
        a5 += d2 * bf2f(hv.z >> 16)    + b1.y;
        a6 += d2 * bf2f(hv.w & 0xffff) + b1.z;
        a7 += d2 * bf2f(hv.w >> 16)    + b1.w;
        float4 o0 = {a0, a1, a2, a3};
        float4 o1 = {a4, a5, a6, a7};
        *(float4*)&out[(size_t)wid * 64 + c0] = o0;
        *(float4*)&out[(size_t)wid * 64 + c0 + 4] = o1;
    }
}

// ---------------- global mean pool (batch sorted; one wave/graph) ----------------

__global__ void k_pool_seg(const float* __restrict__ h, const int* __restrict__ gstart,
                           const int* __restrict__ gend, float* __restrict__ out) {
    int g = (blockIdx.x * blockDim.x + threadIdx.x) >> 6;
    int lane = threadIdx.x & 63;
    if (g >= GG) return;
    int s = gstart[g], e = gend[g];
    int quad = lane >> 4;
    int l16 = lane & 15;
    const float4* h4 = (const float4*)h;
    float4 acc = {0.f, 0.f, 0.f, 0.f};
    for (int r = s + quad; r < e; r += 4) {
        float4 v = h4[(size_t)r * 16 + l16];
        acc.x += v.x; acc.y += v.y; acc.z += v.z; acc.w += v.w;
    }
    acc.x += __shfl_down(acc.x, 32);
    acc.y += __shfl_down(acc.y, 32);
    acc.z += __shfl_down(acc.z, 32);
    acc.w += __shfl_down(acc.w, 32);
    acc.x += __shfl_down(acc.x, 16);
    acc.y += __shfl_down(acc.y, 16);
    acc.z += __shfl_down(acc.z, 16);
    acc.w += __shfl_down(acc.w, 16);
    if (lane < 16) {
        float inv = 1.0f / fmaxf((float)(e - s), 1.0f);
        acc.x *= inv; acc.y *= inv; acc.z *= inv; acc.w *= inv;
        ((float4*)out)[(size_t)g * 16 + l16] = acc;
    }
}

extern "C" void kernel_launch(void* const* d_in, const int* in_sizes, int n_in,
                              void* d_out, int out_size, void* d_ws, size_t ws_size,
                              hipStream_t stream) {
    const float* x     = (const float*)d_in[0];
    const int*   ei    = (const int*)d_in[1];
    const int*   batch = (const int*)d_in[2];
    const float* W1 = (const float*)d_in[3];
    const float* b1 = (const float*)d_in[4];
    const float* W2 = (const float*)d_in[5];
    const float* b2 = (const float*)d_in[6];
    const float* W3 = (const float*)d_in[7];
    const float* b3 = (const float*)d_in[8];
    float* out = (float*)d_out;

    const int* src = ei;
    const int* dst = ei + NE;

    char* p = (char*)d_ws;
    auto alloc = [&](size_t nbytes) -> void* {
        void* r = (void*)p;
        p += (nbytes + 255) & ~((size_t)255);
        return r;
    };
    // total ~51.9 MB (within proven envelope)
    int*   ctrl    = (int*)alloc((size_t)NCTRL * 4);
    int*   cursor  = ctrl;
    int*   gstart  = ctrl + NBUCK;
    int*   gend    = ctrl + NBUCK + GG;
    int*   cnt     = (int*)alloc((size_t)NN * 4);
    float* dinv    = (float*)alloc((size_t)NN * 4);
    int*   csr_idx = (int*)alloc((size_t)NN * SLOT * 4);
    unsigned short* bufA16 = (unsigned short*)alloc((size_t)NN * 128 * 2);   // gemm out
    float* bufB    = (float*)alloc((size_t)NN * 128 * 4);                    // pool in
    unsigned short* WT1 = (unsigned short*)alloc(128 * 128 * 2);
    unsigned short* WT2 = (unsigned short*)alloc(128 * 128 * 2);
    unsigned short* WT3 = (unsigned short*)alloc(128 * 64 * 2);
    // aliases on bufB (stream order makes these safe):
    unsigned* ebuf = (unsigned*)bufB;                 // build staging, dead after binB
    unsigned short* bufH16 = (unsigned short*)bufB;   // agg128 out / gemm L2-L3 in

    const int B = 256;
    auto nb = [](long long n, int b) { return (int)((n + b - 1) / b); };
    const int gemm_grid = (NN + 63) / 64;
    const int agg128_grid = (NN / 2) / 4 * 8;   // 50000 blocks (4 slices x XCD pairs)
    const int agg64_grid  = (NN / 4) / 4 * 8;   // 25000 blocks (2 slices x XCD quads)

    // --- prep (incl. ctrl zeroing) + build ---
    k_wprep<<<64, 256, 0, stream>>>(W1, W2, W3, WT1, WT2, WT3, ctrl);
    k_binA<<<NBLK_A, 256, 0, stream>>>(src, dst, cursor, ebuf);
    k_binB<<<NBUCK, 256, 0, stream>>>(cursor, ebuf, cnt, csr_idx, dinv, batch,
                                      gstart, gend);

    // --- layer 1 (A = fp32 x, converted inline) ---
    k_gemm_mfma<128, true><<<gemm_grid, 256, 0, stream>>>(x, WT1, bufA16);
    k_agg128s<true><<<agg128_grid, B, 0, stream>>>(bufA16, cnt, csr_idx, dinv, b1, bufH16);

    // --- layer 2 ---
    k_gemm_mfma<128, false><<<gemm_grid, 256, 0, stream>>>(bufH16, WT2, bufA16);
    k_agg128s<true><<<agg128_grid, B, 0, stream>>>(bufA16, cnt, csr_idx, dinv, b2, bufH16);

    // --- layer 3 ---
    k_gemm_mfma<64, false><<<gemm_grid, 256, 0, stream>>>(bufH16, WT3, bufA16);
    k_agg64s<<<agg64_grid, B, 0, stream>>>(bufA16, cnt, csr_idx, dinv, b3, bufB);

    // --- global mean pool ---
    k_pool_seg<<<nb((long long)GG * 64, B), B, 0, stream>>>(bufB, gstart, gend, out);
}

// Round 17
// 273.524 us; speedup vs baseline: 1.3906x; 1.3906x over previous
//
#include <hip/hip_runtime.h>
#include <hip/hip_bf16.h>

// ---------------------------------------------------------------------------
// 3-layer GCN + global mean pool, MI355X — round 16: revert to R14 (proven)
//
// R15 post-mortem: channel-sliced XCD agg REGRESSED (271->380): blockIdx->XCD
// affinity didn't hold (FETCH 105->118 MB) and 4x waves quadrupled loop
// overhead (VALU 58%). Arithmetic: R14's per-XCD fetch (8 x 12.8 MB = 105 MB)
// is already the compulsory minimum under dst-partitioning, moving at the
// ~3.8 TB/s random-gather fill rate. Reverting to the 270.9 us R14 kernel.
// ---------------------------------------------------------------------------

constexpr int NN   = 50000;   // nodes (divisible by 16)
constexpr int NE   = 800000;  // edges
constexpr int GG   = 512;     // graphs
constexpr int SLOT = 64;      // padded slots/node

constexpr int NBUCK  = (NN + 127) / 128;       // 391 buckets of 128 nodes
constexpr int BCAP   = 2560;                   // per-bucket capacity
constexpr int EPB    = 2048;                   // edges per binA block
constexpr int NBLK_A = (NE + EPB - 1) / EPB;   // 391 blocks
constexpr int NCTRL  = NBUCK + 2 * GG;         // cursor + gstart + gend words

using shortx8 = __attribute__((ext_vector_type(8))) short;   // 8 bf16 = 4 VGPRs
using f32x4   = __attribute__((ext_vector_type(4))) float;

__device__ __forceinline__ unsigned short f2bf(float f) {
    __hip_bfloat16 h = __float2bfloat16(f);   // RNE
    return *(unsigned short*)&h;
}
__device__ __forceinline__ float bf2f(unsigned u16) {
    return __uint_as_float(u16 << 16);
}

// ---------------- W prep (bf16 col-major) + ctrl zeroing (fused memset) ----------
__global__ void k_wprep(const float* __restrict__ W1, const float* __restrict__ W2,
                        const float* __restrict__ W3, unsigned short* __restrict__ WT1,
                        unsigned short* __restrict__ WT2, unsigned short* __restrict__ WT3,
                        int* __restrict__ ctrl) {
    int i = blockIdx.x * blockDim.x + threadIdx.x;
    if (i < NCTRL) ctrl[i] = 0;
    if (i < 128 * 128) {
        int k = i >> 7, n = i & 127;
        WT1[n * 128 + k] = f2bf(W1[i]);
        WT2[n * 128 + k] = f2bf(W2[i]);
    }
    if (i < 128 * 64) {
        int k = i >> 6, n = i & 63;
        WT3[n * 128 + k] = f2bf(W3[i]);
    }
}

// ---------------- build phase A: bin edges by 128-node bucket (R11-proven) -------
__global__ __launch_bounds__(256) void k_binA(const int* __restrict__ src,
                                              const int* __restrict__ dst,
                                              int* __restrict__ cursor,
                                              unsigned* __restrict__ ebuf) {
    __shared__ int hist[512];
    __shared__ int lstart[512];
    __shared__ int gbase[NBUCK];
    __shared__ int lcur[NBUCK];
    __shared__ unsigned stage[EPB];

    int tid = threadIdx.x;
    int e0 = blockIdx.x * EPB;
    int nloc = min(EPB, NE - e0);

    hist[tid] = 0;
    hist[tid + 256] = 0;
    __syncthreads();
    for (int k = 0; k < EPB / 256; ++k) {
        int e = e0 + k * 256 + tid;
        if (e < NE) atomicAdd(&hist[dst[e] >> 7], 1);
    }
    __syncthreads();

    int v0 = hist[tid];
    lstart[tid] = v0;
    __syncthreads();
    for (int off = 1; off < 256; off <<= 1) {
        int t = (tid >= off) ? lstart[tid - off] : 0;
        __syncthreads();
        lstart[tid] += t;
        __syncthreads();
    }
    int v1 = hist[256 + tid];
    lstart[256 + tid] = v1;
    __syncthreads();
    for (int off = 1; off < 256; off <<= 1) {
        int t = (tid >= off) ? lstart[256 + tid - off] : 0;
        __syncthreads();
        lstart[256 + tid] += t;
        __syncthreads();
    }
    int lowTotal = lstart[255];
    int ex0 = lstart[tid] - v0;
    int ex1 = lstart[256 + tid] - v1 + lowTotal;
    __syncthreads();
    lstart[tid] = ex0;
    lstart[256 + tid] = ex1;
    __syncthreads();

    for (int i = tid; i < NBUCK; i += 256) {
        int h = hist[i];
        gbase[i] = (h > 0) ? atomicAdd(&cursor[i], h) : 0;
        lcur[i] = lstart[i];
    }
    __syncthreads();

    for (int k = 0; k < EPB / 256; ++k) {
        int e = e0 + k * 256 + tid;
        if (e < NE) {
            int d = dst[e];
            int pos = atomicAdd(&lcur[d >> 7], 1);
            stage[pos] = (unsigned)src[e] | ((unsigned)d << 16);
        }
    }
    __syncthreads();

    for (int i = tid; i < nloc; i += 256) {
        unsigned rec = stage[i];
        int bk = rec >> 23;
        int gpos = gbase[bk] + (i - lstart[bk]);
        if (gpos < BCAP) ebuf[(size_t)bk * BCAP + gpos] = rec;
    }
}

// ---------------- build phase B: per-bucket CSR in LDS + aux (R10-proven) --------
__global__ __launch_bounds__(256) void k_binB(const int* __restrict__ cursor,
                                              const unsigned* __restrict__ ebuf,
                                              int* __restrict__ cnt,
                                              int* __restrict__ csr_idx,
                                              float* __restrict__ dinv,
                                              const int* __restrict__ batch,
                                              int* __restrict__ gstart,
                                              int* __restrict__ gend) {
    __shared__ unsigned stage[BCAP];
    __shared__ unsigned short ordered[BCAP];
    __shared__ int ncnt[128];
    __shared__ int nstart[128];
    __shared__ int ncur[128];

    int bk = blockIdx.x;
    int tid = threadIdx.x;
    int n0 = bk << 7;
    int count = min(cursor[bk], BCAP);

    if (tid < 128) ncnt[tid] = 0;
    __syncthreads();
    for (int i = tid; i < count; i += 256) {
        unsigned rec = ebuf[(size_t)bk * BCAP + i];
        stage[i] = rec;
        atomicAdd(&ncnt[(rec >> 16) & 127], 1);
    }
    __syncthreads();
    if (tid < 128) nstart[tid] = ncnt[tid];
    __syncthreads();
    for (int off = 1; off < 128; off <<= 1) {
        int t = (tid >= off && tid < 128) ? nstart[tid - off] : 0;
        __syncthreads();
        if (tid < 128) nstart[tid] += t;
        __syncthreads();
    }
    if (tid < 128) { nstart[tid] -= ncnt[tid]; ncur[tid] = nstart[tid]; }
    __syncthreads();
    for (int i = tid; i < count; i += 256) {
        unsigned rec = stage[i];
        int nl = (rec >> 16) & 127;
        int p = atomicAdd(&ncur[nl], 1);
        ordered[p] = (unsigned short)(rec & 0xFFFFu);
    }
    __syncthreads();
    {
        int nl = tid >> 1, h = tid & 1;
        int node = n0 + nl;
        if (node < NN) {
            int c = min(ncnt[nl], SLOT);
            int s0 = nstart[nl];
            for (int k = h; k < c; k += 2)
                csr_idx[(size_t)node * SLOT + k] = ordered[s0 + k];
        }
    }
    if (tid < 128) {
        int node = n0 + tid;
        if (node < NN) {
            int c = ncnt[tid];
            cnt[node] = c;
            dinv[node] = rsqrtf((float)c + 1.0f);   // +1 self loop
            int b = batch[node];
            if (node == 0 || batch[node - 1] != b) gstart[b] = node;
            if (node == NN - 1 || batch[node + 1] != b) gend[b] = node + 1;
        }
    }
}

// ---------------- MFMA GEMM (R12-proven): out16[NN,DO] = A[NN,128] @ W ----------
template <int DO, bool AFP32>
__global__ __launch_bounds__(256) void k_gemm_mfma(const void* __restrict__ Ain,
                                                   const unsigned short* __restrict__ WT,
                                                   unsigned short* __restrict__ out16) {
    int tid = threadIdx.x;
    int wave = tid >> 6, lane = tid & 63;
    int row0 = blockIdx.x * 64 + wave * 16;
    if (row0 >= NN) return;
    int lrow = lane & 15;
    int lk8 = lane >> 4;
    int row = row0 + lrow;

    shortx8 afrag[4];
    if constexpr (AFP32) {
        const float* A = (const float*)Ain;
#pragma unroll
        for (int ks = 0; ks < 4; ++ks) {
            int k0 = ks * 32 + lk8 * 8;
            float4 f0 = *(const float4*)&A[(size_t)row * 128 + k0];
            float4 f1 = *(const float4*)&A[(size_t)row * 128 + k0 + 4];
            union { shortx8 v; unsigned short u[8]; } t;
            t.u[0] = f2bf(f0.x); t.u[1] = f2bf(f0.y);
            t.u[2] = f2bf(f0.z); t.u[3] = f2bf(f0.w);
            t.u[4] = f2bf(f1.x); t.u[5] = f2bf(f1.y);
            t.u[6] = f2bf(f1.z); t.u[7] = f2bf(f1.w);
            afrag[ks] = t.v;
        }
    } else {
        const unsigned short* A = (const unsigned short*)Ain;
#pragma unroll
        for (int ks = 0; ks < 4; ++ks)
            afrag[ks] = *(const shortx8*)&A[(size_t)row * 128 + ks * 32 + lk8 * 8];
    }

    constexpr int NT = DO / 16;
    f32x4 acc[NT];
#pragma unroll
    for (int t = 0; t < NT; ++t) acc[t] = {0.f, 0.f, 0.f, 0.f};

#pragma unroll
    for (int t = 0; t < NT; ++t) {
#pragma unroll
        for (int ks = 0; ks < 4; ++ks) {
            shortx8 b = *(const shortx8*)&WT[(size_t)(t * 16 + lrow) * 128 + ks * 32 + lk8 * 8];
            acc[t] = __builtin_amdgcn_mfma_f32_16x16x32_bf16(afrag[ks], b, acc[t], 0, 0, 0);
        }
    }

#pragma unroll
    for (int t = 0; t < NT; ++t) {
#pragma unroll
        for (int r = 0; r < 4; ++r) {
            int orow = row0 + lk8 * 4 + r;
            out16[(size_t)orow * DO + t * 16 + lrow] = f2bf(acc[t][r]);
        }
    }
}

// ---------------- agg DO=128: shfl gather, EXEC-safe (uniform loop bounds) -------
template <bool RELU>
__global__ void k_agg128(const unsigned short* __restrict__ h16,
                         const int* __restrict__ cnt, const int* __restrict__ csr_idx,
                         const float* __restrict__ dinv, const float* __restrict__ b,
                         unsigned short* __restrict__ out16) {
    int wid = (blockIdx.x * blockDim.x + threadIdx.x) >> 6;   // wave-uniform
    int lane = threadIdx.x & 63;
    if (wid >= NN) return;                                    // wave-uniform exit
    int quad = lane >> 4;            // 4 edge streams
    int l16 = lane & 15;             // 16 lanes x 8 bf16 ch = 128 ch
    int n = min(cnt[wid], SLOT);     // wave-uniform
    float dv = dinv[wid];

    // cache this node's records (one lane = one edge); lanes >= n hold 0
    int rec = 0; float wl = 0.f;
    if (lane < n) {
        rec = csr_idx[wid * SLOT + lane];   // coalesced 256 B
        wl = dv * dinv[rec];
    }

    const uint4* h4 = (const uint4*)h16;
    float a0=0,a1=0,a2=0,a3=0,a4=0,a5=0,a6=0,a7=0;

    // main loop: bound is wave-uniform -> exec full at every __shfl
    int jb_end = n & ~15;
    for (int jb = 0; jb < jb_end; jb += 16) {
        int j0 = jb + quad;          // j0, j0+4, j0+8, j0+12 all < jb_end <= n
        int s0 = __shfl(rec, j0);
        int s1 = __shfl(rec, j0 + 4);
        int s2 = __shfl(rec, j0 + 8);
        int s3 = __shfl(rec, j0 + 12);
        float w0 = __shfl(wl, j0);
        float w1 = __shfl(wl, j0 + 4);
        float w2 = __shfl(wl, j0 + 8);
        float w3 = __shfl(wl, j0 + 12);
        uint4 v0 = h4[(size_t)s0 * 16 + l16];
        uint4 v1 = h4[(size_t)s1 * 16 + l16];
        uint4 v2 = h4[(size_t)s2 * 16 + l16];
        uint4 v3 = h4[(size_t)s3 * 16 + l16];
        a0 += w0*bf2f(v0.x & 0xffff) + w1*bf2f(v1.x & 0xffff) + w2*bf2f(v2.x & 0xffff) + w3*bf2f(v3.x & 0xffff);
        a1 += w0*bf2f(v0.x >> 16)    + w1*bf2f(v1.x >> 16)    + w2*bf2f(v2.x >> 16)    + w3*bf2f(v3.x >> 16);
        a2 += w0*bf2f(v0.y & 0xffff) + w1*bf2f(v1.y & 0xffff) + w2*bf2f(v2.y & 0xffff) + w3*bf2f(v3.y & 0xffff);
        a3 += w0*bf2f(v0.y >> 16)    + w1*bf2f(v1.y >> 16)    + w2*bf2f(v2.y >> 16)    + w3*bf2f(v3.y >> 16);
        a4 += w0*bf2f(v0.z & 0xffff) + w1*bf2f(v1.z & 0xffff) + w2*bf2f(v2.z & 0xffff) + w3*bf2f(v3.z & 0xffff);
        a5 += w0*bf2f(v0.z >> 16)    + w1*bf2f(v1.z >> 16)    + w2*bf2f(v2.z >> 16)    + w3*bf2f(v3.z >> 16);
        a6 += w0*bf2f(v0.w & 0xffff) + w1*bf2f(v1.w & 0xffff) + w2*bf2f(v2.w & 0xffff) + w3*bf2f(v3.w & 0xffff);
        a7 += w0*bf2f(v0.w >> 16)    + w1*bf2f(v1.w >> 16)    + w2*bf2f(v2.w >> 16)    + w3*bf2f(v3.w >> 16);
    }

    // remainder: one uniform block; shfls converged (lane idx masked), loads guarded
    {
        int i0 = jb_end + quad;
        int i1 = i0 + 4;
        int i2 = i0 + 8;
        int i3 = i0 + 12;                      // <= 48+3+12 = 63
        int s0 = __shfl(rec, i0 & 63); float w0 = __shfl(wl, i0 & 63);
        int s1 = __shfl(rec, i1 & 63); float w1 = __shfl(wl, i1 & 63);
        int s2 = __shfl(rec, i2 & 63); float w2 = __shfl(wl, i2 & 63);
        int s3 = __shfl(rec, i3 & 63); float w3 = __shfl(wl, i3 & 63);
        if (i0 < n) {
            uint4 v = h4[(size_t)s0 * 16 + l16];
            a0 += w0*bf2f(v.x & 0xffff); a1 += w0*bf2f(v.x >> 16);
            a2 += w0*bf2f(v.y & 0xffff); a3 += w0*bf2f(v.y >> 16);
            a4 += w0*bf2f(v.z & 0xffff); a5 += w0*bf2f(v.z >> 16);
            a6 += w0*bf2f(v.w & 0xffff); a7 += w0*bf2f(v.w >> 16);
        }
        if (i1 < n) {
            uint4 v = h4[(size_t)s1 * 16 + l16];
            a0 += w1*bf2f(v.x & 0xffff); a1 += w1*bf2f(v.x >> 16);
            a2 += w1*bf2f(v.y & 0xffff); a3 += w1*bf2f(v.y >> 16);
            a4 += w1*bf2f(v.z & 0xffff); a5 += w1*bf2f(v.z >> 16);
            a6 += w1*bf2f(v.w & 0xffff); a7 += w1*bf2f(v.w >> 16);
        }
        if (i2 < n) {
            uint4 v = h4[(size_t)s2 * 16 + l16];
            a0 += w2*bf2f(v.x & 0xffff); a1 += w2*bf2f(v.x >> 16);
            a2 += w2*bf2f(v.y & 0xffff); a3 += w2*bf2f(v.y >> 16);
            a4 += w2*bf2f(v.z & 0xffff); a5 += w2*bf2f(v.z >> 16);
            a6 += w2*bf2f(v.w & 0xffff); a7 += w2*bf2f(v.w >> 16);
        }
        if (i3 < n) {
            uint4 v = h4[(size_t)s3 * 16 + l16];
            a0 += w3*bf2f(v.x & 0xffff); a1 += w3*bf2f(v.x >> 16);
            a2 += w3*bf2f(v.y & 0xffff); a3 += w3*bf2f(v.y >> 16);
            a4 += w3*bf2f(v.z & 0xffff); a5 += w3*bf2f(v.z >> 16);
            a6 += w3*bf2f(v.w & 0xffff); a7 += w3*bf2f(v.w >> 16);
        }
    }

    a0 += __shfl_down(a0, 32); a1 += __shfl_down(a1, 32);
    a2 += __shfl_down(a2, 32); a3 += __shfl_down(a3, 32);
    a4 += __shfl_down(a4, 32); a5 += __shfl_down(a5, 32);
    a6 += __shfl_down(a6, 32); a7 += __shfl_down(a7, 32);
    a0 += __shfl_down(a0, 16); a1 += __shfl_down(a1, 16);
    a2 += __shfl_down(a2, 16); a3 += __shfl_down(a3, 16);
    a4 += __shfl_down(a4, 16); a5 += __shfl_down(a5, 16);
    a6 += __shfl_down(a6, 16); a7 += __shfl_down(a7, 16);
    if (lane < 16) {
        float d2 = dv * dv;
        uint4 hv = h4[(size_t)wid * 16 + l16];
        float4 b0 = *(const float4*)&b[l16 * 8];
        float4 b1 = *(const float4*)&b[l16 * 8 + 4];
        a0 += d2 * bf2f(hv.x & 0xffff) + b0.x;
        a1 += d2 * bf2f(hv.x >> 16)    + b0.y;
        a2 += d2 * bf2f(hv.y & 0xffff) + b0.z;
        a3 += d2 * bf2f(hv.y >> 16)    + b0.w;
        a4 += d2 * bf2f(hv.z & 0xffff) + b1.x;
        a5 += d2 * bf2f(hv.z >> 16)    + b1.y;
        a6 += d2 * bf2f(hv.w & 0xffff) + b1.z;
        a7 += d2 * bf2f(hv.w >> 16)    + b1.w;
        if (RELU) {
            a0 = fmaxf(a0, 0.f); a1 = fmaxf(a1, 0.f); a2 = fmaxf(a2, 0.f); a3 = fmaxf(a3, 0.f);
            a4 = fmaxf(a4, 0.f); a5 = fmaxf(a5, 0.f); a6 = fmaxf(a6, 0.f); a7 = fmaxf(a7, 0.f);
        }
        union { uint4 v; unsigned short u[8]; } o;
        o.u[0] = f2bf(a0); o.u[1] = f2bf(a1); o.u[2] = f2bf(a2); o.u[3] = f2bf(a3);
        o.u[4] = f2bf(a4); o.u[5] = f2bf(a5); o.u[6] = f2bf(a6); o.u[7] = f2bf(a7);
        *(uint4*)&out16[(size_t)wid * 128 + l16 * 8] = o.v;
    }
}

// ---------------- agg DO=64: shfl gather, EXEC-safe (uniform loop bounds) --------
__global__ void k_agg64(const unsigned short* __restrict__ h16,
                        const int* __restrict__ cnt, const int* __restrict__ csr_idx,
                        const float* __restrict__ dinv, const float* __restrict__ b,
                        float* __restrict__ out) {
    int wid = (blockIdx.x * blockDim.x + threadIdx.x) >> 6;
    int lane = threadIdx.x & 63;
    if (wid >= NN) return;
    int oct = lane >> 3;             // 8 edge streams
    int l8 = lane & 7;               // 8 lanes x 8 bf16 ch = 64 ch
    int n = min(cnt[wid], SLOT);
    float dv = dinv[wid];

    int rec = 0; float wl = 0.f;
    if (lane < n) {
        rec = csr_idx[wid * SLOT + lane];
        wl = dv * dinv[rec];
    }

    const uint4* h4 = (const uint4*)h16;
    float a0=0,a1=0,a2=0,a3=0,a4=0,a5=0,a6=0,a7=0;

    int jb_end = n & ~15;
    for (int jb = 0; jb < jb_end; jb += 16) {
        int j0 = jb + oct;           // j0, j0+8 both < jb_end <= n
        int s0 = __shfl(rec, j0);
        int s1 = __shfl(rec, j0 + 8);
        float w0 = __shfl(wl, j0);
        float w1 = __shfl(wl, j0 + 8);
        uint4 v0 = h4[(size_t)s0 * 8 + l8];
        uint4 v1 = h4[(size_t)s1 * 8 + l8];
        a0 += w0 * bf2f(v0.x & 0xffff) + w1 * bf2f(v1.x & 0xffff);
        a1 += w0 * bf2f(v0.x >> 16)    + w1 * bf2f(v1.x >> 16);
        a2 += w0 * bf2f(v0.y & 0xffff) + w1 * bf2f(v1.y & 0xffff);
        a3 += w0 * bf2f(v0.y >> 16)    + w1 * bf2f(v1.y >> 16);
        a4 += w0 * bf2f(v0.z & 0xffff) + w1 * bf2f(v1.z & 0xffff);
        a5 += w0 * bf2f(v0.z >> 16)    + w1 * bf2f(v1.z >> 16);
        a6 += w0 * bf2f(v0.w & 0xffff) + w1 * bf2f(v1.w & 0xffff);
        a7 += w0 * bf2f(v0.w >> 16)    + w1 * bf2f(v1.w >> 16);
    }
    {
        int i0 = jb_end + oct;
        int i1 = i0 + 8;                       // <= 48+7+8 = 63
        int s0 = __shfl(rec, i0 & 63); float w0 = __shfl(wl, i0 & 63);
        int s1 = __shfl(rec, i1 & 63); float w1 = __shfl(wl, i1 & 63);
        if (i0 < n) {
            uint4 v = h4[(size_t)s0 * 8 + l8];
            a0 += w0*bf2f(v.x & 0xffff); a1 += w0*bf2f(v.x >> 16);
            a2 += w0*bf2f(v.y & 0xffff); a3 += w0*bf2f(v.y >> 16);
            a4 += w0*bf2f(v.z & 0xffff); a5 += w0*bf2f(v.z >> 16);
            a6 += w0*bf2f(v.w & 0xffff); a7 += w0*bf2f(v.w >> 16);
        }
        if (i1 < n) {
            uint4 v = h4[(size_t)s1 * 8 + l8];
            a0 += w1*bf2f(v.x & 0xffff); a1 += w1*bf2f(v.x >> 16);
            a2 += w1*bf2f(v.y & 0xffff); a3 += w1*bf2f(v.y >> 16);
            a4 += w1*bf2f(v.z & 0xffff); a5 += w1*bf2f(v.z >> 16);
            a6 += w1*bf2f(v.w & 0xffff); a7 += w1*bf2f(v.w >> 16);
        }
    }

    a0 += __shfl_down(a0, 32); a1 += __shfl_down(a1, 32);
    a2 += __shfl_down(a2, 32); a3 += __shfl_down(a3, 32);
    a4 += __shfl_down(a4, 32); a5 += __shfl_down(a5, 32);
    a6 += __shfl_down(a6, 32); a7 += __shfl_down(a7, 32);
    a0 += __shfl_down(a0, 16); a1 += __shfl_down(a1, 16);
    a2 += __shfl_down(a2, 16); a3 += __shfl_down(a3, 16);
    a4 += __shfl_down(a4, 16); a5 += __shfl_down(a5, 16);
    a6 += __shfl_down(a6, 16); a7 += __shfl_down(a7, 16);
    a0 += __shfl_down(a0, 8);  a1 += __shfl_down(a1, 8);
    a2 += __shfl_down(a2, 8);  a3 += __shfl_down(a3, 8);
    a4 += __shfl_down(a4, 8);  a5 += __shfl_down(a5, 8);
    a6 += __shfl_down(a6, 8);  a7 += __shfl_down(a7, 8);
    if (lane < 8) {
        float d2 = dv * dv;
        uint4 hv = h4[(size_t)wid * 8 + l8];
        float4 b0 = *(const float4*)&b[l8 * 8];
        float4 b1 = *(const float4*)&b[l8 * 8 + 4];
        a0 += d2 * bf2f(hv.x & 0xffff) + b0.x;
        a1 += d2 * bf2f(hv.x >> 16)    + b0.y;
        a2 += d2 * bf2f(hv.y & 0xffff) + b0.z;
        a3 += d2 * bf2f(hv.y >> 16)    + b0.w;
        a4 += d2 * bf2f(hv.z & 0xffff) + b1.x;
        a5 += d2 * bf2f(hv.z >> 16)    + b1.y;
        a6 += d2 * bf2f(hv.w & 0xffff) + b1.z;
        a7 += d2 * bf2f(hv.w >> 16)    + b1.w;
        float4 o0 = {a0, a1, a2, a3};
        float4 o1 = {a4, a5, a6, a7};
        *(float4*)&out[(size_t)wid * 64 + l8 * 8] = o0;
        *(float4*)&out[(size_t)wid * 64 + l8 * 8 + 4] = o1;
    }
}

// ---------------- global mean pool (batch sorted; one wave/graph) ----------------

__global__ void k_pool_seg(const float* __restrict__ h, const int* __restrict__ gstart,
                           const int* __restrict__ gend, float* __restrict__ out) {
    int g = (blockIdx.x * blockDim.x + threadIdx.x) >> 6;
    int lane = threadIdx.x & 63;
    if (g >= GG) return;
    int s = gstart[g], e = gend[g];
    int quad = lane >> 4;
    int l16 = lane & 15;
    const float4* h4 = (const float4*)h;
    float4 acc = {0.f, 0.f, 0.f, 0.f};
    for (int r = s + quad; r < e; r += 4) {
        float4 v = h4[(size_t)r * 16 + l16];
        acc.x += v.x; acc.y += v.y; acc.z += v.z; acc.w += v.w;
    }
    acc.x += __shfl_down(acc.x, 32);
    acc.y += __shfl_down(acc.y, 32);
    acc.z += __shfl_down(acc.z, 32);
    acc.w += __shfl_down(acc.w, 32);
    acc.x += __shfl_down(acc.x, 16);
    acc.y += __shfl_down(acc.y, 16);
    acc.z += __shfl_down(acc.z, 16);
    acc.w += __shfl_down(acc.w, 16);
    if (lane < 16) {
        float inv = 1.0f / fmaxf((float)(e - s), 1.0f);
        acc.x *= inv; acc.y *= inv; acc.z *= inv; acc.w *= inv;
        ((float4*)out)[(size_t)g * 16 + l16] = acc;
    }
}

extern "C" void kernel_launch(void* const* d_in, const int* in_sizes, int n_in,
                              void* d_out, int out_size, void* d_ws, size_t ws_size,
                              hipStream_t stream) {
    const float* x     = (const float*)d_in[0];
    const int*   ei    = (const int*)d_in[1];
    const int*   batch = (const int*)d_in[2];
    const float* W1 = (const float*)d_in[3];
    const float* b1 = (const float*)d_in[4];
    const float* W2 = (const float*)d_in[5];
    const float* b2 = (const float*)d_in[6];
    const float* W3 = (const float*)d_in[7];
    const float* b3 = (const float*)d_in[8];
    float* out = (float*)d_out;

    const int* src = ei;
    const int* dst = ei + NE;

    char* p = (char*)d_ws;
    auto alloc = [&](size_t nbytes) -> void* {
        void* r = (void*)p;
        p += (nbytes + 255) & ~((size_t)255);
        return r;
    };
    // total ~51.9 MB (within proven envelope)
    int*   ctrl    = (int*)alloc((size_t)NCTRL * 4);
    int*   cursor  = ctrl;
    int*   gstart  = ctrl + NBUCK;
    int*   gend    = ctrl + NBUCK + GG;
    int*   cnt     = (int*)alloc((size_t)NN * 4);
    float* dinv    = (float*)alloc((size_t)NN * 4);
    int*   csr_idx = (int*)alloc((size_t)NN * SLOT * 4);
    unsigned short* bufA16 = (unsigned short*)alloc((size_t)NN * 128 * 2);   // gemm out
    float* bufB    = (float*)alloc((size_t)NN * 128 * 4);                    // pool in
    unsigned short* WT1 = (unsigned short*)alloc(128 * 128 * 2);
    unsigned short* WT2 = (unsigned short*)alloc(128 * 128 * 2);
    unsigned short* WT3 = (unsigned short*)alloc(128 * 64 * 2);
    // aliases on bufB (stream order makes these safe):
    unsigned* ebuf = (unsigned*)bufB;                 // build staging, dead after binB
    unsigned short* bufH16 = (unsigned short*)bufB;   // agg128 out / gemm L2-L3 in

    const int B = 256;
    auto nb = [](long long n, int b) { return (int)((n + b - 1) / b); };
    const int gemm_grid = (NN + 63) / 64;
    const int agg_grid = nb((long long)NN * 64, B);

    // --- prep (incl. ctrl zeroing) + build ---
    k_wprep<<<64, 256, 0, stream>>>(W1, W2, W3, WT1, WT2, WT3, ctrl);
    k_binA<<<NBLK_A, 256, 0, stream>>>(src, dst, cursor, ebuf);
    k_binB<<<NBUCK, 256, 0, stream>>>(cursor, ebuf, cnt, csr_idx, dinv, batch,
                                      gstart, gend);

    // --- layer 1 (A = fp32 x, converted inline) ---
    k_gemm_mfma<128, true><<<gemm_grid, 256, 0, stream>>>(x, WT1, bufA16);
    k_agg128<true><<<agg_grid, B, 0, stream>>>(bufA16, cnt, csr_idx, dinv, b1, bufH16);

    // --- layer 2 ---
    k_gemm_mfma<128, false><<<gemm_grid, 256, 0, stream>>>(bufH16, WT2, bufA16);
    k_agg128<true><<<agg_grid, B, 0, stream>>>(bufA16, cnt, csr_idx, dinv, b2, bufH16);

    // --- layer 3 ---
    k_gemm_mfma<64, false><<<gemm_grid, 256, 0, stream>>>(bufH16, WT3, bufA16);
    k_agg64<<<agg_grid, B, 0, stream>>>(bufA16, cnt, csr_idx, dinv, b3, bufB);

    // --- global mean pool ---
    k_pool_seg<<<nb((long long)GG * 64, B), B, 0, stream>>>(bufB, gstart, gend, out);
}